// Round 16
// baseline (40.171 us; speedup 1.0000x reference)
//
#include <hip/hip_runtime.h>

// BertWordEmbedder: B=64, T=512, H=768, W=256, D=256
// TWO kernels, no intermediate we:
//   prep_wt2: proj_w [768][256] f32 -> wt2 TILED bf16 [ct=16][kc=96][16col][8k]
//   fused:    R16: block = (b, 16-word group) x full D  (was 32) ->
//             LDS 27 KB -> 4-5 blocks/CU resident (was 3): deeper cross-block
//             overlap of HBM phase A with MFMA phase B, shorter tails.
//             Phase A: R8-proven pair streaming (2 pairs/wave) -> A[16][776].
//             Phase B: zero-barrier K-loop, A from LDS, B direct from wt2 (L2),
//             wave = 16x64 out tile, ping-pong reg prefetch. + bias -> out.
// Empty words: zero A row -> out = bias (matches reference).
// ws: [0) wt2 393216 B

#define NB 64
#define NT 512
#define NH 768
#define NW 256
#define ND 256
#define PAD 8
#define ROWE (NH + PAD)   // 776

typedef __attribute__((ext_vector_type(8))) short short8;
typedef __attribute__((ext_vector_type(4))) float f32x4;
typedef __attribute__((ext_vector_type(4))) float float4v;
typedef __attribute__((ext_vector_type(4))) unsigned short ushort4v;

__device__ __forceinline__ unsigned short f2bf(float f) {
    union { float f; unsigned u; } v; v.f = f;
    unsigned r = v.u + 0x7fffu + ((v.u >> 16) & 1u);  // RNE
    return (unsigned short)(r >> 16);
}

// proj_w -> tiled wt2: element (k, col) at [((col>>4)*96 + (k>>3))*16 + (col&15)]*8 + (k&7)
__global__ void prep_wt2(const float* __restrict__ w, unsigned short* __restrict__ wt2) {
    __shared__ float tile[32][33];   // [kk][cc]
    const int tid = threadIdx.x, n = blockIdx.x;
    const int tx = tid & 31, ty = tid >> 5;
    const int k0 = (n % 24) * 32, n0 = (n / 24) * 32;
    #pragma unroll
    for (int i = 0; i < 4; ++i)
        tile[ty + 8 * i][tx] = w[(size_t)(k0 + ty + 8 * i) * ND + n0 + tx];
    __syncthreads();
    if (tid < 128) {
        const int cc = tid & 31, q = tid >> 5;        // q = 0..3 (8-k chunk)
        const int col = n0 + cc;
        ushort4v u0, u1;
        #pragma unroll
        for (int j = 0; j < 4; ++j) u0[j] = f2bf(tile[q * 8 + j][cc]);
        #pragma unroll
        for (int j = 0; j < 4; ++j) u1[j] = f2bf(tile[q * 8 + 4 + j][cc]);
        size_t off = (((size_t)(col >> 4) * 96 + (k0 >> 3) + q) * 16 + (col & 15)) * 8;
        *(ushort4v*)&wt2[off]     = u0;
        *(ushort4v*)&wt2[off + 4] = u1;
    }
}

// fused pool+GEMM. 1024 blocks = (b, 16-word group), 256 thr = 4 waves.
__global__ __launch_bounds__(256, 4)
void fused(const float* __restrict__ hs, const int* __restrict__ wid,
           const unsigned short* __restrict__ wt2, const float* __restrict__ pb,
           float* __restrict__ out) {
    __shared__ unsigned short A[16][ROWE];   // 24832 B
    __shared__ int swid[NT];
    __shared__ int sb[17];

    const int tid = threadIdx.x, bid = blockIdx.x;
    const int wave = tid >> 6, lane = tid & 63;
    const int b = bid >> 4, w0 = (bid & 15) * 16;

    // stage word ids; parallel bounds (17 searches)
    swid[tid]       = wid[b * NT + tid];
    swid[tid + 256] = wid[b * NT + tid + 256];
    __syncthreads();
    if (tid <= 16) {
        int v = w0 + tid, lo = 0, hi = NT;
        while (lo < hi) { int mid = (lo + hi) >> 1; if (swid[mid] < v) lo = mid + 1; else hi = mid; }
        sb[tid] = lo;
    }
    __syncthreads();

    // ---- Phase A: pool 8 word-pairs (R8-proven streaming), 2 pairs/wave ----
    const float* base = hs + (size_t)b * NT * NH + lane * 4;
    #pragma unroll 1
    for (int pp = 0; pp < 2; ++pp) {
        const int p = wave * 2 + pp;                 // pair 0..7, rows 2p,2p+1
        const int s = sb[2 * p], m = sb[2 * p + 1], e = sb[2 * p + 2];

        float4v a0c0 = {0,0,0,0}, a0c1 = {0,0,0,0}, a0c2 = {0,0,0,0};
        float4v a1c0 = {0,0,0,0}, a1c1 = {0,0,0,0}, a1c2 = {0,0,0,0};
#define ROUTE(t, v0, v1, v2) {                                                \
        if ((t) < m) {                                                        \
            _Pragma("unroll") for (int q = 0; q < 4; ++q) {                   \
                a0c0[q] += (v0)[q]; a0c1[q] += (v1)[q]; a0c2[q] += (v2)[q]; } \
        } else {                                                              \
            _Pragma("unroll") for (int q = 0; q < 4; ++q) {                   \
                a1c0[q] += (v0)[q]; a1c1[q] += (v1)[q]; a1c2[q] += (v2)[q]; } \
        }                                                                     \
    }
        int t = s;
        for (; t + 2 <= e; t += 2) {                 // 6 loads in flight
            float4v v[2][3];
            #pragma unroll
            for (int u = 0; u < 2; ++u) {
                const float* p2 = base + (size_t)(t + u) * NH;
                v[u][0] = *(const float4v*)(p2);
                v[u][1] = *(const float4v*)(p2 + 256);
                v[u][2] = *(const float4v*)(p2 + 512);
            }
            #pragma unroll
            for (int u = 0; u < 2; ++u) ROUTE(t + u, v[u][0], v[u][1], v[u][2]);
        }
        if (t < e) {
            const float* p2 = base + (size_t)t * NH;
            float4v v0 = *(const float4v*)(p2);
            float4v v1 = *(const float4v*)(p2 + 256);
            float4v v2 = *(const float4v*)(p2 + 512);
            ROUTE(t, v0, v1, v2);
        }
#undef ROUTE
        int c0n = m - s; if (c0n < 1) c0n = 1;
        int c1n = e - m; if (c1n < 1) c1n = 1;
        const float s0 = 1.0f / (float)c0n, s1 = 1.0f / (float)c1n;
        ushort4v u;
        #pragma unroll
        for (int q = 0; q < 4; ++q) u[q] = f2bf(a0c0[q] * s0);
        *(ushort4v*)&A[2 * p][lane * 4] = u;
        #pragma unroll
        for (int q = 0; q < 4; ++q) u[q] = f2bf(a0c1[q] * s0);
        *(ushort4v*)&A[2 * p][256 + lane * 4] = u;
        #pragma unroll
        for (int q = 0; q < 4; ++q) u[q] = f2bf(a0c2[q] * s0);
        *(ushort4v*)&A[2 * p][512 + lane * 4] = u;
        #pragma unroll
        for (int q = 0; q < 4; ++q) u[q] = f2bf(a1c0[q] * s1);
        *(ushort4v*)&A[2 * p + 1][lane * 4] = u;
        #pragma unroll
        for (int q = 0; q < 4; ++q) u[q] = f2bf(a1c1[q] * s1);
        *(ushort4v*)&A[2 * p + 1][256 + lane * 4] = u;
        #pragma unroll
        for (int q = 0; q < 4; ++q) u[q] = f2bf(a1c2[q] * s1);
        *(ushort4v*)&A[2 * p + 1][512 + lane * 4] = u;
    }
    __syncthreads();

    // ---- Phase B: GEMM [16x768]x[768x256], zero in-loop barriers ----
    const int cl = lane & 15, kg = lane >> 4;
    const int c0w = wave * 64;
    const unsigned short* bgp = wt2 + (size_t)(wave * 4) * 12288 + kg * 128 + cl * 8;

    short8 a0, a1, b0[4], b1[4];
    f32x4 acc[4];
    #pragma unroll
    for (int nt = 0; nt < 4; ++nt)
        #pragma unroll
        for (int r = 0; r < 4; ++r) acc[nt][r] = 0.f;

#define LDA(d, ks) { d = *(const short8*)&A[cl][(ks) * 32 + kg * 8]; }
#define LDB(d, ks) { _Pragma("unroll")                                        \
                     for (int nt = 0; nt < 4; ++nt)                           \
                         d[nt] = *(const short8*)(bgp + nt * 12288 + (ks) * 512); }
#define MM(a, bb) { _Pragma("unroll")                                         \
                    for (int nt = 0; nt < 4; ++nt)                            \
                        acc[nt] = __builtin_amdgcn_mfma_f32_16x16x32_bf16(a, bb[nt], acc[nt], 0, 0, 0); }

    LDA(a0, 0); LDB(b0, 0);
    #pragma unroll 1
    for (int i = 0; i < 12; ++i) {
        const int ks = 2 * i;
        LDA(a1, ks + 1); LDB(b1, ks + 1);
        MM(a0, b0);
        if (i < 11) { LDA(a0, ks + 2); LDB(b0, ks + 2); }
        MM(a1, b1);
    }
#undef LDA
#undef LDB
#undef MM

    float bv[4];
    #pragma unroll
    for (int nt = 0; nt < 4; ++nt) bv[nt] = pb[c0w + nt * 16 + cl];

    // C/D layout: col=lane&15, row=(lane>>4)*4+r  [proven R1-R15]
    #pragma unroll
    for (int nt = 0; nt < 4; ++nt)
        #pragma unroll
        for (int r = 0; r < 4; ++r)
            out[((size_t)b * NW + w0 + kg * 4 + r) * ND + c0w + nt * 16 + cl]
                = acc[nt][r] + bv[nt];
}

extern "C" void kernel_launch(void* const* d_in, const int* in_sizes, int n_in,
                              void* d_out, int out_size, void* d_ws, size_t ws_size,
                              hipStream_t stream) {
    const float* hs  = (const float*)d_in[0];
    const int*   wid = (const int*)d_in[1];
    const float* pw  = (const float*)d_in[2];
    const float* pb  = (const float*)d_in[3];
    float* out = (float*)d_out;

    unsigned short* wt2 = (unsigned short*)d_ws;     // 393216 B

    prep_wt2<<<192, 256, 0, stream>>>(pw, wt2);
    fused<<<NB * (NW / 16), 256, 0, stream>>>(hs, wid, wt2, pb, out);
}